// Round 9
// baseline (161.923 us; speedup 1.0000x reference)
//
#include <hip/hip_runtime.h>
#include <hip/hip_bf16.h>
#include <stdint.h>
#include <stddef.h>

// ---------- types ----------
typedef short bf16x8 __attribute__((ext_vector_type(8)));   // 8 bf16 (4 VGPRs)
typedef short bf16x4 __attribute__((ext_vector_type(4)));   // 4 bf16 (2 VGPRs)
typedef float f32x4 __attribute__((ext_vector_type(4)));
typedef unsigned short us4 __attribute__((ext_vector_type(4)));

#define MFMA16(a, b, c) __builtin_amdgcn_mfma_f32_16x16x32_bf16((a), (b), (c), 0, 0, 0)

static constexpr int BB = 2, SS = 2048, DD = 1024, HH = 16, HD = 64;
static constexpr int MTOK = BB * SS;  // 4096

union U8 { unsigned int u[4]; bf16x8 v; };

// f32 -> bf16 round-to-nearest-even
__device__ __forceinline__ unsigned short f2bf(float x) {
  unsigned int u = __float_as_uint(x);
  u += 0x7fffu + ((u >> 16) & 1u);
  return (unsigned short)(u >> 16);
}

// pack 2 f32 -> 2 bf16 in one inst (lo -> bits[15:0])
__device__ __forceinline__ unsigned int cvtpk(float lo, float hi) {
  unsigned int r;
  asm("v_cvt_pk_bf16_f32 %0, %1, %2" : "=v"(r) : "v"(lo), "v"(hi));
  return r;
}

// async global->LDS, 16B per lane; LDS dest is wave-uniform base (+lane*16 by HW)
__device__ __forceinline__ void gload16(const void* g, void* l) {
  __builtin_amdgcn_global_load_lds(
      (const __attribute__((address_space(1))) void*)g,
      (__attribute__((address_space(3))) void*)l, 16, 0, 0);
}

// ---------- kernel 1: f32 -> bf16 conversion, WEIGHTS ONLY (4MB f32) ----------
__global__ void cvt_w(const float* __restrict__ Wq, const float* __restrict__ Wk,
                      const float* __restrict__ Wv, const float* __restrict__ Wo,
                      unsigned short* __restrict__ wqkv, unsigned short* __restrict__ wo) {
  const int job = blockIdx.y;
  const float* src;
  unsigned short* dst;
  switch (job) {
    case 0: src = Wq; dst = wqkv;               break;
    case 1: src = Wk; dst = wqkv + DD * DD;     break;
    case 2: src = Wv; dst = wqkv + 2 * DD * DD; break;
    default: src = Wo; dst = wo;                break;
  }
  const int i = (blockIdx.x * 256 + threadIdx.x) * 8;  // 512*256*8 = DD*DD
  const float4 a = *(const float4*)(src + i);
  const float4 b = *(const float4*)(src + i + 4);
  bf16x8 o;
  o[0] = (short)f2bf(a.x); o[1] = (short)f2bf(a.y);
  o[2] = (short)f2bf(a.z); o[3] = (short)f2bf(a.w);
  o[4] = (short)f2bf(b.x); o[5] = (short)f2bf(b.y);
  o[6] = (short)f2bf(b.z); o[7] = (short)f2bf(b.w);
  *(bf16x8*)(dst + i) = o;
}

// ---------- kernel 2: fused QKV projection (R9) ----------
// A (f32 activations) NEVER touches LDS: per-lane frag = 8 consecutive f32,
// loaded as 2x global_load_dwordx4 (lanes g4=0..3 of a row = 128B contiguous,
// L2-resident panel shared by same-XCD blocks), cvt_pk -> bf16 frags.
// Issued BEFORE the barrier so L2 latency drains under the B-stage barrier.
// B (bf16 weights) via proven global_load_lds + XOR-swizzle tile (0 conflicts).
// LDS 16KB; 2-barrier loop as R4.
__global__ __launch_bounds__(256) void gemm_qkv(
    const float* __restrict__ qf32, const float* __restrict__ kf32,
    const float* __restrict__ vf32, const unsigned short* __restrict__ wqkv,
    unsigned short* __restrict__ Qh, unsigned short* __restrict__ Kh,
    unsigned short* __restrict__ Vt) {
  __shared__ unsigned short sB[128 * 64] __attribute__((aligned(16)));   // 16KB
  const int lin = blockIdx.x;
  const int swz = (lin & 7) * 96 + (lin >> 3);  // 768 = 8 * 96 (XCD swizzle)
  const int n0 = (swz % 24) * 128, m0 = (swz / 24) * 128;
  const int proj = n0 >> 10;  // 0:Q 1:K 2:V
  const float* A = proj == 0 ? qf32 : (proj == 1 ? kf32 : vf32);
  const int w = threadIdx.x >> 6, l = threadIdx.x & 63;
  const int wr = w >> 1, wc = w & 1, row = l & 15, g4 = l >> 4;
  const int rk = row & 7;

  // B staging: wave w covers rows [w*32,+32), 4 gloads x 8 rows (128B row)
  const int bRow = l >> 3;            // row within 8-row group
  const int bCh = (l & 7) ^ bRow;     // fetched chunk for LDS slot (l&7)
  const unsigned short* gB = wqkv + (size_t)(n0 + w * 32 + bRow) * 1024 + bCh * 8;
  // A direct: lane reads A[m0 + wr*64 + mi*16 + row][kt + kk*32 + g4*8 ..+7]
  const float* gA = A + (size_t)(m0 + wr * 64 + row) * 1024 + g4 * 8;

  const f32x4 z = {0.f, 0.f, 0.f, 0.f};
  f32x4 acc[4][4];
#pragma unroll
  for (int i = 0; i < 4; ++i)
#pragma unroll
    for (int j = 0; j < 4; ++j) acc[i][j] = z;

  for (int kt = 0; kt < 1024; kt += 64) {
    // ---- stage B (bf16, 4 gloads) ----
#pragma unroll
    for (int i = 0; i < 4; ++i)
      gload16(gB + (size_t)(i * 8) * 1024 + kt, &sB[(w * 32 + i * 8) * 64]);
    // ---- issue kk=0 A-frag loads (register, in flight across barrier) ----
    f32x4 av0[4][2];
#pragma unroll
    for (int mi = 0; mi < 4; ++mi) {
      const float* p = gA + (size_t)(mi * 16) * 1024 + kt;
      av0[mi][0] = *(const f32x4*)(p);
      av0[mi][1] = *(const f32x4*)(p + 4);
    }
    __syncthreads();  // drains B vmcnt -> sB ready (A loads keep flying)
    // ---- issue kk=1 A-frag loads (hidden under kk=0 compute) ----
    f32x4 av1[4][2];
#pragma unroll
    for (int mi = 0; mi < 4; ++mi) {
      const float* p = gA + (size_t)(mi * 16) * 1024 + kt + 32;
      av1[mi][0] = *(const f32x4*)(p);
      av1[mi][1] = *(const f32x4*)(p + 4);
    }
    // ---- kk = 0 ----
    {
      bf16x8 af[4], bfr[4];
      const int ch = ((0 * 4 + g4) ^ rk) << 3;
#pragma unroll
      for (int mi = 0; mi < 4; ++mi) {
        U8 u;
        u.u[0] = cvtpk(av0[mi][0][0], av0[mi][0][1]);
        u.u[1] = cvtpk(av0[mi][0][2], av0[mi][0][3]);
        u.u[2] = cvtpk(av0[mi][1][0], av0[mi][1][1]);
        u.u[3] = cvtpk(av0[mi][1][2], av0[mi][1][3]);
        af[mi] = u.v;
      }
#pragma unroll
      for (int ni = 0; ni < 4; ++ni)
        bfr[ni] = *(const bf16x8*)(&sB[(wc * 64 + ni * 16 + row) * 64 + ch]);
#pragma unroll
      for (int mi = 0; mi < 4; ++mi)
#pragma unroll
        for (int ni = 0; ni < 4; ++ni)
          acc[mi][ni] = MFMA16(af[mi], bfr[ni], acc[mi][ni]);
    }
    // ---- kk = 1 ----
    {
      bf16x8 af[4], bfr[4];
      const int ch = ((1 * 4 + g4) ^ rk) << 3;
#pragma unroll
      for (int mi = 0; mi < 4; ++mi) {
        U8 u;
        u.u[0] = cvtpk(av1[mi][0][0], av1[mi][0][1]);
        u.u[1] = cvtpk(av1[mi][0][2], av1[mi][0][3]);
        u.u[2] = cvtpk(av1[mi][1][0], av1[mi][1][1]);
        u.u[3] = cvtpk(av1[mi][1][2], av1[mi][1][3]);
        af[mi] = u.v;
      }
#pragma unroll
      for (int ni = 0; ni < 4; ++ni)
        bfr[ni] = *(const bf16x8*)(&sB[(wc * 64 + ni * 16 + row) * 64 + ch]);
#pragma unroll
      for (int mi = 0; mi < 4; ++mi)
#pragma unroll
        for (int ni = 0; ni < 4; ++ni)
          acc[mi][ni] = MFMA16(af[mi], bfr[ni], acc[mi][ni]);
    }
    __syncthreads();  // sB reads done before next stage
  }

  // epilogue: Qh,Kh [B,H,S,64]; V transposed Vt [B,H,64,S]
#pragma unroll
  for (int mi = 0; mi < 4; ++mi) {
    const int mbase = m0 + wr * 64 + mi * 16 + g4 * 4;  // token row
    const int bb = mbase >> 11, ss = mbase & 2047;
#pragma unroll
    for (int ni = 0; ni < 4; ++ni) {
      const int c = n0 + wc * 64 + ni * 16 + row;
      const int cc = c & 1023, h = cc >> 6, d = cc & 63;
      if (proj == 0) {
        unsigned short* p = Qh + (((size_t)bb * HH + h) * SS + ss) * HD + d;
#pragma unroll
        for (int r = 0; r < 4; ++r) p[(size_t)r * HD] = f2bf(acc[mi][ni][r]);
      } else if (proj == 1) {
        unsigned short* p = Kh + (((size_t)bb * HH + h) * SS + ss) * HD + d;
#pragma unroll
        for (int r = 0; r < 4; ++r) p[(size_t)r * HD] = f2bf(acc[mi][ni][r]);
      } else {
        us4 pk;
#pragma unroll
        for (int r = 0; r < 4; ++r) pk[r] = f2bf(acc[mi][ni][r]);
        *(us4*)(Vt + (((size_t)bb * HH + h) * HD + d) * SS + ss) = pk;
      }
    }
  }
}

// ---------- kernel 3: causal flash attention (R5 paired version — measured best) ----------
__global__ __launch_bounds__(512, 2) void attn_fwd(const unsigned short* __restrict__ Qh,
                                                   const unsigned short* __restrict__ Kh,
                                                   const unsigned short* __restrict__ Vt,
                                                   unsigned short* __restrict__ ctx) {
  __shared__ unsigned short sK[2][128 * 64] __attribute__((aligned(16)));   // 2x16KB
  __shared__ unsigned short sVT[2][64 * 128] __attribute__((aligned(16)));  // 2x16KB
  const int w = threadIdx.x >> 6, l = threadIdx.x & 63;
  const int row = l & 15, g4 = l >> 4;
  const int qg = w & 3, kh = w >> 2;   // q-group, k-half
  const int ko = kh * 64;              // k offset within tile
  const int bh = blockIdx.x, pair = blockIdx.y;
  const size_t bhS = (size_t)bh * SS;
  const int bb = bh >> 4, h = bh & 15;

  const int kLane = l >> 3;            // staging: row-in-group 0..7 (K tile)
  const int kCh = (l & 7) ^ kLane;     // fetched chunk16 (key = row&7)
  const unsigned short* gvBase = Vt + (size_t)bh * HD * SS;

  const f32x4 z = {0.f, 0.f, 0.f, 0.f};
  constexpr float C1 = 0.18033688f;    // 0.125 * log2(e)
  constexpr float C2 = -17.3123405f;   // -12 * log2(e)

  for (int half = 0; half < 2; ++half) {
    const int qi = half ? (15 - pair) : pair;
    const int q0 = qi * 128;
    const int qw = q0 + qg * 32;       // wave's q base (32 rows)

    bf16x8 qf[2][2];
#pragma unroll
    for (int mi = 0; mi < 2; ++mi)
#pragma unroll
      for (int kk = 0; kk < 2; ++kk)
        qf[mi][kk] = *(const bf16x8*)(Qh + (bhS + qw + mi * 16 + row) * HD +
                                      kk * 32 + g4 * 8);

    f32x4 o[2][4];
#pragma unroll
    for (int mi = 0; mi < 2; ++mi)
#pragma unroll
      for (int di = 0; di < 4; ++di) o[mi][di] = z;
    float lsum[2] = {0.f, 0.f};

    // ---- stage tile 0 into buf 0 (all 8 waves; K 16 rows/wave, VT 8 rows/wave) ----
    {
      const unsigned short* gk = Kh + (bhS + 0) * HD;
      const unsigned short* gv = gvBase;
#pragma unroll
      for (int i = 0; i < 2; ++i) {
        const int R = w * 16 + i * 8;
        gload16(gk + (size_t)(R + kLane) * HD + kCh * 8, &sK[0][R * 64]);
      }
#pragma unroll
      for (int i = 0; i < 2; ++i) {
        const int R = w * 8 + i * 4;
        const int vrow = R + g4;
        gload16(gv + (size_t)vrow * SS + ((row ^ (vrow & 15)) * 8), &sVT[0][R * 128]);
      }
    }
    __syncthreads();
    int cur = 0;

    for (int kt = 0; kt <= qi; ++kt) {
      // ---- prefetch next tile into other buffer (in flight across compute) ----
      if (kt < qi) {
        const unsigned short* gk = Kh + (bhS + (kt + 1) * 128) * HD;
        const unsigned short* gv = gvBase + (kt + 1) * 128;
        const int nb = cur ^ 1;
#pragma unroll
        for (int i = 0; i < 2; ++i) {
          const int R = w * 16 + i * 8;
          gload16(gk + (size_t)(R + kLane) * HD + kCh * 8, &sK[nb][R * 64]);
        }
#pragma unroll
        for (int i = 0; i < 2; ++i) {
          const int R = w * 8 + i * 4;
          const int vrow = R + g4;
          gload16(gv + (size_t)vrow * SS + ((row ^ (vrow & 15)) * 8), &sVT[nb][R * 128]);
        }
      }

      // ---- QK^T (swapped): sc[mi][ni]: k = ko+ni*16+4*g4+r, q = qw+mi*16+row ----
      f32x4 sc[2][4];
#pragma unroll
      for (int mi = 0; mi < 2; ++mi)
#pragma unroll
        for (int ni = 0; ni < 4; ++ni) sc[mi][ni] = z;
      __builtin_amdgcn_s_setprio(1);
#pragma unroll
      for (int kk = 0; kk < 2; ++kk)
#pragma unroll
        for (int ni = 0; ni < 4; ++ni) {
          const bf16x8 kf = *(const bf16x8*)(
              &sK[cur][(ko + ni * 16 + row) * 64 + (((kk * 4 + g4) ^ (row & 7)) << 3)]);
          sc[0][ni] = MFMA16(kf, qf[0][kk], sc[0][ni]);
          sc[1][ni] = MFMA16(kf, qf[1][kk], sc[1][ni]);
        }
      __builtin_amdgcn_s_setprio(0);

      // ---- softmax (static max) + in-register P (pi-trick A-frags) ----
      bf16x8 pa[2][2];
      const bool diag = (kt == qi);
#pragma unroll
      for (int mi = 0; mi < 2; ++mi) {
        float ls = 0.f;
        if (!diag) {
#pragma unroll
          for (int kk2 = 0; kk2 < 2; ++kk2) {
            U8 t;
#pragma unroll
            for (int b = 0; b < 2; ++b) {
              const f32x4 s4 = sc[mi][kk2 * 2 + b];
              const float p0 = __builtin_amdgcn_exp2f(fmaf(s4[0], C1, C2));
              const float p1 = __builtin_amdgcn_exp2f(fmaf(s4[1], C1, C2));
              const float p2 = __builtin_amdgcn_exp2f(fmaf(s4[2], C1, C2));
              const float p3 = __builtin_amdgcn_exp2f(fmaf(s4[3], C1, C2));
              ls += (p0 + p1) + (p2 + p3);
              t.u[b * 2 + 0] = cvtpk(p0, p1);
              t.u[b * 2 + 1] = cvtpk(p2, p3);
            }
            pa[mi][kk2] = t.v;
          }
        } else {  // diag tile: mask k > q (relative indices share base kt*128=q0)
          const int relB = ko + 4 * g4 - (qg * 32 + mi * 16 + row);
#pragma unroll
          for (int kk2 = 0; kk2 < 2; ++kk2) {
            U8 t;
#pragma unroll
            for (int b = 0; b < 2; ++b) {
              const f32x4 s4 = sc[mi][kk2 * 2 + b];
              const int base = relB + (kk2 * 2 + b) * 16;
              float t0 = fmaf(s4[0], C1, C2); if (base + 0 > 0) t0 = -1e30f;
              float t1 = fmaf(s4[1], C1, C2); if (base + 1 > 0) t1 = -1e30f;
              float t2 = fmaf(s4[2], C1, C2); if (base + 2 > 0) t2 = -1e30f;
              float t3 = fmaf(s4[3], C1, C2); if (base + 3 > 0) t3 = -1e30f;
              const float p0 = __builtin_amdgcn_exp2f(t0);
              const float p1 = __builtin_amdgcn_exp2f(t1);
              const float p2 = __builtin_amdgcn_exp2f(t2);
              const float p3 = __builtin_amdgcn_exp2f(t3);
              ls += (p0 + p1) + (p2 + p3);
              t.u[b * 2 + 0] = cvtpk(p0, p1);
              t.u[b * 2 + 1] = cvtpk(p2, p3);
            }
            pa[mi][kk2] = t.v;
          }
        }
        lsum[mi] += ls;
      }

      // ---- PV: O[32 q][64 d] += P * V ; vf built per-lane to match pa's k-perm ----
      __builtin_amdgcn_s_setprio(1);
#pragma unroll
      for (int kk2 = 0; kk2 < 2; ++kk2) {
        const int c16a = kh * 8 + kk2 * 4 + (g4 >> 1);  // b=0 chunk16 (global)
        const int c16b = c16a + 2;                      // b=1 chunk16
        const int h8 = (g4 & 1) * 4;                    // 8B half within chunk
#pragma unroll
        for (int di = 0; di < 4; ++di) {
          const int d = di * 16 + row;
          const unsigned short* vr = &sVT[cur][d * 128];
          const bf16x4 vlo = *(const bf16x4*)(vr + ((c16a ^ row) << 3) + h8);
          const bf16x4 vhi = *(const bf16x4*)(vr + ((c16b ^ row) << 3) + h8);
          const bf16x8 vf = __builtin_shufflevector(vlo, vhi, 0, 1, 2, 3, 4, 5, 6, 7);
          o[0][di] = MFMA16(pa[0][kk2], vf, o[0][di]);
          o[1][di] = MFMA16(pa[1][kk2], vf, o[1][di]);
        }
      }
      __builtin_amdgcn_s_setprio(0);
      __syncthreads();  // buffer-reuse fence + drains prefetch
      cur ^= 1;
    }

    // ---- combine k-halves (static max -> pure addition), then write ctx ----
#pragma unroll
    for (int mi = 0; mi < 2; ++mi) {
      lsum[mi] += __shfl_xor(lsum[mi], 16);
      lsum[mi] += __shfl_xor(lsum[mi], 32);  // full sum over this k-half
    }
    f32x4* sO4 = (f32x4*)(&sK[0][0]);        // 2048 slots = 32KB scratch
    float* sL = (float*)(&sVT[0][0]);        // 128 f32: hi-half lsums
    float* sL2 = sL + 128;                   // 128 f32: totals
    if (kh) {
#pragma unroll
      for (int mi = 0; mi < 2; ++mi) {
        if (g4 == 0) sL[(qg * 2 + mi) * 16 + row] = lsum[mi];
#pragma unroll
        for (int di = 0; di < 4; ++di)
          sO4[((qg * 2 + mi) * 4 + g4) * 64 + di * 16 + row] = o[mi][di];
      }
    }
    __syncthreads();
    if (!kh) {
#pragma unroll
      for (int mi = 0; mi < 2; ++mi) {
        const float lt = lsum[mi] + sL[(qg * 2 + mi) * 16 + row];
        if (g4 == 0) sL2[(qg * 2 + mi) * 16 + row] = lt;  // redistribute to PV q-map
      }
#pragma unroll
      for (int mi = 0; mi < 2; ++mi) {
        const f32x4 lv = *(const f32x4*)(sL2 + (qg * 2 + mi) * 16 + g4 * 4);
#pragma unroll
        for (int di = 0; di < 4; ++di) {
          const f32x4 po =
              o[mi][di] + sO4[((qg * 2 + mi) * 4 + g4) * 64 + di * 16 + row];
#pragma unroll
          for (int r = 0; r < 4; ++r) {
            const int ss = qw + mi * 16 + g4 * 4 + r;
            ctx[((size_t)bb * SS + ss) * DD + h * HD + di * 16 + row] =
                f2bf(po[r] * (1.f / lv[r]));
          }
        }
      }
    }
    __syncthreads();  // scratch reads done before next half's staging
  }
}

// ---------- kernel 4: output projection (f32 out), bf16 gload_lds core ----------
__global__ void gemm_out(const unsigned short* __restrict__ ctx,
                         const unsigned short* __restrict__ wo, float* __restrict__ Out) {
  __shared__ unsigned short sA[128 * 64] __attribute__((aligned(16)));
  __shared__ unsigned short sB[128 * 64] __attribute__((aligned(16)));
  const int lin = blockIdx.x;
  const int swz = (lin & 7) * 32 + (lin >> 3);  // 256 = 8 * 32
  const int n0 = (swz % 8) * 128, m0 = (swz / 8) * 128;
  const int w = threadIdx.x >> 6, l = threadIdx.x & 63;
  const int wr = w >> 1, wc = w & 1, row = l & 15, g4 = l >> 4;
  const int sRow = l >> 3, sCh = (l & 7) ^ sRow;
  const unsigned short* ga = ctx + (size_t)(m0 + w * 32 + sRow) * 1024 + sCh * 8;
  const unsigned short* gb = wo + (size_t)(n0 + w * 32 + sRow) * 1024 + sCh * 8;
  unsigned short* la = sA + (w * 32) * 64;
  unsigned short* lb = sB + (w * 32) * 64;
  const int rk = row & 7;
  const f32x4 z = {0.f, 0.f, 0.f, 0.f};
  f32x4 acc[4][4];
#pragma unroll
  for (int i = 0; i < 4; ++i)
#pragma unroll
    for (int j = 0; j < 4; ++j) acc[i][j] = z;
  for (int kt = 0; kt < 1024; kt += 64) {
#pragma unroll
    for (int i = 0; i < 4; ++i) {
      gload16(ga + (size_t)(i * 8) * 1024, la + (i * 8) * 64);
      gload16(gb + (size_t)(i * 8) * 1024, lb + (i * 8) * 64);
    }
    ga += 64;
    gb += 64;
    __syncthreads();
#pragma unroll
    for (int kk = 0; kk < 2; ++kk) {
      bf16x8 af[4], bfr[4];
      const int ch = ((kk * 4 + g4) ^ rk) << 3;
#pragma unroll
      for (int mi = 0; mi < 4; ++mi)
        af[mi] = *(const bf16x8*)(sA + (wr * 64 + mi * 16 + row) * 64 + ch);
#pragma unroll
      for (int ni = 0; ni < 4; ++ni)
        bfr[ni] = *(const bf16x8*)(sB + (wc * 64 + ni * 16 + row) * 64 + ch);
#pragma unroll
      for (int mi = 0; mi < 4; ++mi)
#pragma unroll
        for (int ni = 0; ni < 4; ++ni)
          acc[mi][ni] = MFMA16(af[mi], bfr[ni], acc[mi][ni]);
    }
    __syncthreads();
  }
#pragma unroll
  for (int mi = 0; mi < 4; ++mi) {
    const int mbase = m0 + wr * 64 + mi * 16 + g4 * 4;
#pragma unroll
    for (int ni = 0; ni < 4; ++ni) {
      const int c = n0 + wc * 64 + ni * 16 + row;
      float* p = Out + (size_t)mbase * DD + c;
#pragma unroll
      for (int r = 0; r < 4; ++r) p[(size_t)r * DD] = acc[mi][ni][r];
    }
  }
}

// ---------- launch ----------
extern "C" void kernel_launch(void* const* d_in, const int* in_sizes, int n_in,
                              void* d_out, int out_size, void* d_ws, size_t ws_size,
                              hipStream_t stream) {
  (void)in_sizes; (void)n_in; (void)out_size; (void)ws_size;
  const float* q  = (const float*)d_in[0];
  const float* k  = (const float*)d_in[1];
  const float* v  = (const float*)d_in[2];
  // d_in[3] = causal mask, recomputed analytically
  const float* Wq = (const float*)d_in[4];
  const float* Wk = (const float*)d_in[5];
  const float* Wv = (const float*)d_in[6];
  const float* Wo = (const float*)d_in[7];

  unsigned short* ws = (unsigned short*)d_ws;
  const size_t NTD = (size_t)MTOK * DD;  // 4096*1024
  unsigned short* wqkv = ws;
  unsigned short* wo   = wqkv + (size_t)3 * DD * DD;
  unsigned short* Qh   = wo + (size_t)DD * DD;
  unsigned short* Kh   = Qh + NTD;
  unsigned short* Vt   = Kh + NTD;
  unsigned short* ctx  = Vt + NTD;  // total 40MB of ws

  cvt_w<<<dim3(512, 4), 256, 0, stream>>>(Wq, Wk, Wv, Wo, wqkv, wo);
  gemm_qkv<<<768, 256, 0, stream>>>(q, k, v, wqkv, Qh, Kh, Vt);
  attn_fwd<<<dim3(32, 8), 512, 0, stream>>>(Qh, Kh, Vt, ctx);
  gemm_out<<<256, 256, 0, stream>>>(ctx, wo, (float*)d_out);
}

// Round 10
// 111.252 us; speedup vs baseline: 1.4555x; 1.4555x over previous
//
#include <hip/hip_runtime.h>
#include <hip/hip_bf16.h>
#include <stdint.h>
#include <stddef.h>

// ---------- types ----------
typedef short bf16x8 __attribute__((ext_vector_type(8)));   // 8 bf16 (4 VGPRs)
typedef short bf16x4 __attribute__((ext_vector_type(4)));   // 4 bf16 (2 VGPRs)
typedef float f32x4 __attribute__((ext_vector_type(4)));
typedef unsigned short us4 __attribute__((ext_vector_type(4)));

#define MFMA16(a, b, c) __builtin_amdgcn_mfma_f32_16x16x32_bf16((a), (b), (c), 0, 0, 0)

static constexpr int BB = 2, SS = 2048, DD = 1024, HH = 16, HD = 64;
static constexpr int MTOK = BB * SS;  // 4096

union U8 { unsigned int u[4]; bf16x8 v; };

// f32 -> bf16 round-to-nearest-even
__device__ __forceinline__ unsigned short f2bf(float x) {
  unsigned int u = __float_as_uint(x);
  u += 0x7fffu + ((u >> 16) & 1u);
  return (unsigned short)(u >> 16);
}

// pack 2 f32 -> 2 bf16 in one inst (lo -> bits[15:0])
__device__ __forceinline__ unsigned int cvtpk(float lo, float hi) {
  unsigned int r;
  asm("v_cvt_pk_bf16_f32 %0, %1, %2" : "=v"(r) : "v"(lo), "v"(hi));
  return r;
}

// async global->LDS, 16B per lane; LDS dest is wave-uniform base (+lane*16 by HW)
__device__ __forceinline__ void gload16(const void* g, void* l) {
  __builtin_amdgcn_global_load_lds(
      (const __attribute__((address_space(1))) void*)g,
      (__attribute__((address_space(3))) void*)l, 16, 0, 0);
}

#define BAR() __builtin_amdgcn_s_barrier()
#define VMW8() asm volatile("s_waitcnt vmcnt(8)" ::: "memory")
#define VMW0() asm volatile("s_waitcnt vmcnt(0)" ::: "memory")

// ---------- kernel 1: f32 -> bf16 conversions (q,k,v,Wq,Wk,Wv,Wo) ----------
__global__ void cvt_all(const float* __restrict__ q, const float* __restrict__ k,
                        const float* __restrict__ v, const float* __restrict__ Wq,
                        const float* __restrict__ Wk, const float* __restrict__ Wv,
                        const float* __restrict__ Wo, unsigned short* __restrict__ qb,
                        unsigned short* __restrict__ kb, unsigned short* __restrict__ vb,
                        unsigned short* __restrict__ wqkv, unsigned short* __restrict__ wo) {
  const int job = blockIdx.y;
  const float* src;
  unsigned short* dst;
  int n;
  switch (job) {
    case 0: src = q;  dst = qb;             n = MTOK * DD; break;
    case 1: src = k;  dst = kb;             n = MTOK * DD; break;
    case 2: src = v;  dst = vb;             n = MTOK * DD; break;
    case 3: src = Wq; dst = wqkv;           n = DD * DD;   break;
    case 4: src = Wk; dst = wqkv + DD * DD; n = DD * DD;   break;
    case 5: src = Wv; dst = wqkv + 2 * DD * DD; n = DD * DD; break;
    default: src = Wo; dst = wo;            n = DD * DD;   break;
  }
  const int i = (blockIdx.x * 256 + threadIdx.x) * 8;
  if (i >= n) return;
  const float4 a = *(const float4*)(src + i);
  const float4 b = *(const float4*)(src + i + 4);
  bf16x8 o;
  o[0] = (short)f2bf(a.x); o[1] = (short)f2bf(a.y);
  o[2] = (short)f2bf(a.z); o[3] = (short)f2bf(a.w);
  o[4] = (short)f2bf(b.x); o[5] = (short)f2bf(b.y);
  o[6] = (short)f2bf(b.z); o[7] = (short)f2bf(b.w);
  *(bf16x8*)(dst + i) = o;
}

// ---------- kernel 2: fused QKV projection — 256x256 8-phase schedule (R10) ----------
// T3+T4+T5 per m201 template: 512 thr = 8 waves (2M x 4N), per-wave out 128x64,
// BK=64, 2 K-tiles per iteration in 2 LDS buffers (128KB total), 8 phases/iter
// {dsload quadrant frags | stage | barrier | MFMA(setprio) | [vmcnt] | barrier}.
// Counted vmcnt(8) ONLY at phases 3/7, placed BEFORE the trailing barrier so the
// post-barrier dsloads see all waves' staged data (per-wave vmcnt + barrier =
// block-wide guarantee). Data layout = measured-0-conflict 16B-chunk XOR swizzle
// (slot s of LDS row r holds global chunk s^(r&7); pre-swizzled global source).
__global__ __launch_bounds__(512, 2) void gemm_qkv(
    const unsigned short* __restrict__ qb, const unsigned short* __restrict__ kb,
    const unsigned short* __restrict__ vb, const unsigned short* __restrict__ wqkv,
    unsigned short* __restrict__ Qh, unsigned short* __restrict__ Kh,
    unsigned short* __restrict__ Vt) {
  __shared__ unsigned short sA[2][256 * 64] __attribute__((aligned(16)));  // 2x32KB
  __shared__ unsigned short sB[2][256 * 64] __attribute__((aligned(16)));  // 2x32KB
  const int lin = blockIdx.x;
  const int swz = (lin & 7) * 24 + (lin >> 3);  // 192 = 8 * 24 (bijective XCD swizzle)
  const int m0 = (swz / 12) * 256, n0 = (swz % 12) * 256;
  const int proj = n0 >> 10;  // 0:Q 1:K 2:V (256 | 1024 -> tile within one proj)
  const unsigned short* A = proj == 0 ? qb : (proj == 1 ? kb : vb);
  const int tid = threadIdx.x, wid = tid >> 6, l = tid & 63;
  const int wr2 = wid >> 2, wc4 = wid & 3;     // wave grid 2(M) x 4(N)
  const int row16 = l & 15, g4 = l >> 4;
  const int rk = row16 & 7;
  // staging lane geometry (8 lanes/row x 16B; slot l&7 fetches chunk (l&7)^(l>>3))
  const int sRow = l >> 3, sCh = (l & 7) ^ sRow;
  const unsigned short* gA = A + (size_t)(m0 + wid * 8 + sRow) * 1024 + sCh * 8;
  const unsigned short* gB = wqkv + (size_t)(n0 + wid * 8 + sRow) * 1024 + sCh * 8;

#define STAGE(T, BUF)                                                        \
  {                                                                          \
    _Pragma("unroll") for (int j = 0; j < 4; ++j)                            \
        gload16(gA + (size_t)(j * 64) * 1024 + (T) * 64,                     \
                &sA[BUF][(j * 64 + wid * 8) * 64]);                          \
    _Pragma("unroll") for (int j = 0; j < 4; ++j)                            \
        gload16(gB + (size_t)(j * 64) * 1024 + (T) * 64,                     \
                &sB[BUF][(j * 64 + wid * 8) * 64]);                          \
  }

  const f32x4 z = {0.f, 0.f, 0.f, 0.f};
  f32x4 acc[8][4];
#pragma unroll
  for (int i = 0; i < 8; ++i)
#pragma unroll
    for (int j = 0; j < 4; ++j) acc[i][j] = z;

  bf16x8 afr[2][4][2];   // [mh][m8'][kk]
  bf16x8 bfrg[2][2][2];  // [nh][n4'][kk]

#define DSLOAD_A(MH, BUF)                                                    \
  _Pragma("unroll") for (int m8 = 0; m8 < 4; ++m8)                           \
      _Pragma("unroll") for (int kk = 0; kk < 2; ++kk)                       \
          afr[MH][m8][kk] = *(const bf16x8*)(&sA[BUF][                       \
              (wr2 * 128 + (MH) * 64 + m8 * 16 + row16) * 64 +               \
              (((kk * 4 + g4) ^ rk) << 3)]);
#define DSLOAD_B(NH, BUF)                                                    \
  _Pragma("unroll") for (int n4 = 0; n4 < 2; ++n4)                           \
      _Pragma("unroll") for (int kk = 0; kk < 2; ++kk)                       \
          bfrg[NH][n4][kk] = *(const bf16x8*)(&sB[BUF][                      \
              (wc4 * 64 + (NH) * 32 + n4 * 16 + row16) * 64 +                \
              (((kk * 4 + g4) ^ rk) << 3)]);
#define MFMA_Q(MH, NH)                                                       \
  __builtin_amdgcn_s_setprio(1);                                             \
  _Pragma("unroll") for (int m8 = 0; m8 < 4; ++m8)                           \
      _Pragma("unroll") for (int n4 = 0; n4 < 2; ++n4)                       \
          _Pragma("unroll") for (int kk = 0; kk < 2; ++kk)                   \
              acc[(MH) * 4 + m8][(NH) * 2 + n4] =                            \
                  MFMA16(afr[MH][m8][kk], bfrg[NH][n4][kk],                  \
                         acc[(MH) * 4 + m8][(NH) * 2 + n4]);                 \
  __builtin_amdgcn_s_setprio(0);

  // prologue: K-tiles 0,1 -> bufs 0,1
  STAGE(0, 0)
  STAGE(1, 1)
  VMW8();  // own K0 loads landed (8 younger = K1)
  BAR();   // all waves' K0 landed

  for (int it = 0; it < 8; ++it) {
    const int t2 = 2 * it;
    // ---- phase 0: quadrant (0,0) of buf0 ----
    DSLOAD_A(0, 0) DSLOAD_B(0, 0)
    BAR(); MFMA_Q(0, 0) BAR();
    // ---- phase 1: (1,0) ----
    DSLOAD_A(1, 0)
    BAR(); MFMA_Q(1, 0) BAR();
    // ---- phase 2: (0,1) ----
    DSLOAD_B(1, 0)
    BAR(); MFMA_Q(0, 1) BAR();
    // ---- phase 3: (1,1); stage K(t+2)->buf0 (fully read by ph2); vmcnt for ph4 ----
    if (it < 7) STAGE(t2 + 2, 0)
    BAR(); MFMA_Q(1, 1)
    if (it < 7) { VMW8(); } else { VMW0(); }  // K(t+1) landed (8 younger = ph3 stage)
    BAR();
    // ---- phase 4: quadrant (0,0) of buf1 ----
    DSLOAD_A(0, 1) DSLOAD_B(0, 1)
    BAR(); MFMA_Q(0, 0) BAR();
    // ---- phase 5: (1,0) ----
    DSLOAD_A(1, 1)
    BAR(); MFMA_Q(1, 0) BAR();
    // ---- phase 6: (0,1) ----
    DSLOAD_B(1, 1)
    BAR(); MFMA_Q(0, 1) BAR();
    // ---- phase 7: (1,1); stage K(t+3)->buf1; vmcnt for next ph0 ----
    if (it < 7) STAGE(t2 + 3, 1)
    BAR(); MFMA_Q(1, 1)
    VMW8();  // K(t+2) landed (8 younger = ph7 stage); no-op on last iter
    BAR();
  }
#undef STAGE
#undef DSLOAD_A
#undef DSLOAD_B
#undef MFMA_Q

  // epilogue: Qh,Kh [B,H,S,64]; V transposed Vt [B,H,64,S]
#pragma unroll
  for (int m8 = 0; m8 < 8; ++m8) {
    const int mbase = m0 + wr2 * 128 + m8 * 16 + g4 * 4;  // token row
    const int bb = mbase >> 11, ss = mbase & 2047;
#pragma unroll
    for (int n4 = 0; n4 < 4; ++n4) {
      const int c = n0 + wc4 * 64 + n4 * 16 + row16;
      const int cc = c & 1023, h = cc >> 6, d = cc & 63;
      if (proj == 0) {
        unsigned short* p = Qh + (((size_t)bb * HH + h) * SS + ss) * HD + d;
#pragma unroll
        for (int r = 0; r < 4; ++r) p[(size_t)r * HD] = f2bf(acc[m8][n4][r]);
      } else if (proj == 1) {
        unsigned short* p = Kh + (((size_t)bb * HH + h) * SS + ss) * HD + d;
#pragma unroll
        for (int r = 0; r < 4; ++r) p[(size_t)r * HD] = f2bf(acc[m8][n4][r]);
      } else {
        us4 pk;
#pragma unroll
        for (int r = 0; r < 4; ++r) pk[r] = f2bf(acc[m8][n4][r]);
        *(us4*)(Vt + (((size_t)bb * HH + h) * HD + d) * SS + ss) = pk;
      }
    }
  }
}

// ---------- kernel 3: causal flash attention (R5 paired version — measured best) ----------
__global__ __launch_bounds__(512, 2) void attn_fwd(const unsigned short* __restrict__ Qh,
                                                   const unsigned short* __restrict__ Kh,
                                                   const unsigned short* __restrict__ Vt,
                                                   unsigned short* __restrict__ ctx) {
  __shared__ unsigned short sK[2][128 * 64] __attribute__((aligned(16)));   // 2x16KB
  __shared__ unsigned short sVT[2][64 * 128] __attribute__((aligned(16)));  // 2x16KB
  const int w = threadIdx.x >> 6, l = threadIdx.x & 63;
  const int row = l & 15, g4 = l >> 4;
  const int qg = w & 3, kh = w >> 2;   // q-group, k-half
  const int ko = kh * 64;              // k offset within tile
  const int bh = blockIdx.x, pair = blockIdx.y;
  const size_t bhS = (size_t)bh * SS;
  const int bb = bh >> 4, h = bh & 15;

  const int kLane = l >> 3;            // staging: row-in-group 0..7 (K tile)
  const int kCh = (l & 7) ^ kLane;     // fetched chunk16 (key = row&7)
  const unsigned short* gvBase = Vt + (size_t)bh * HD * SS;

  const f32x4 z = {0.f, 0.f, 0.f, 0.f};
  constexpr float C1 = 0.18033688f;    // 0.125 * log2(e)
  constexpr float C2 = -17.3123405f;   // -12 * log2(e)

  for (int half = 0; half < 2; ++half) {
    const int qi = half ? (15 - pair) : pair;
    const int q0 = qi * 128;
    const int qw = q0 + qg * 32;       // wave's q base (32 rows)

    bf16x8 qf[2][2];
#pragma unroll
    for (int mi = 0; mi < 2; ++mi)
#pragma unroll
      for (int kk = 0; kk < 2; ++kk)
        qf[mi][kk] = *(const bf16x8*)(Qh + (bhS + qw + mi * 16 + row) * HD +
                                      kk * 32 + g4 * 8);

    f32x4 o[2][4];
#pragma unroll
    for (int mi = 0; mi < 2; ++mi)
#pragma unroll
      for (int di = 0; di < 4; ++di) o[mi][di] = z;
    float lsum[2] = {0.f, 0.f};

    // ---- stage tile 0 into buf 0 ----
    {
      const unsigned short* gk = Kh + (bhS + 0) * HD;
      const unsigned short* gv = gvBase;
#pragma unroll
      for (int i = 0; i < 2; ++i) {
        const int R = w * 16 + i * 8;
        gload16(gk + (size_t)(R + kLane) * HD + kCh * 8, &sK[0][R * 64]);
      }
#pragma unroll
      for (int i = 0; i < 2; ++i) {
        const int R = w * 8 + i * 4;
        const int vrow = R + g4;
        gload16(gv + (size_t)vrow * SS + ((row ^ (vrow & 15)) * 8), &sVT[0][R * 128]);
      }
    }
    __syncthreads();
    int cur = 0;

    for (int kt = 0; kt <= qi; ++kt) {
      // ---- prefetch next tile into other buffer ----
      if (kt < qi) {
        const unsigned short* gk = Kh + (bhS + (kt + 1) * 128) * HD;
        const unsigned short* gv = gvBase + (kt + 1) * 128;
        const int nb = cur ^ 1;
#pragma unroll
        for (int i = 0; i < 2; ++i) {
          const int R = w * 16 + i * 8;
          gload16(gk + (size_t)(R + kLane) * HD + kCh * 8, &sK[nb][R * 64]);
        }
#pragma unroll
        for (int i = 0; i < 2; ++i) {
          const int R = w * 8 + i * 4;
          const int vrow = R + g4;
          gload16(gv + (size_t)vrow * SS + ((row ^ (vrow & 15)) * 8), &sVT[nb][R * 128]);
        }
      }

      // ---- QK^T (swapped): sc[mi][ni]: k = ko+ni*16+4*g4+r, q = qw+mi*16+row ----
      f32x4 sc[2][4];
#pragma unroll
      for (int mi = 0; mi < 2; ++mi)
#pragma unroll
        for (int ni = 0; ni < 4; ++ni) sc[mi][ni] = z;
      __builtin_amdgcn_s_setprio(1);
#pragma unroll
      for (int kk = 0; kk < 2; ++kk)
#pragma unroll
        for (int ni = 0; ni < 4; ++ni) {
          const bf16x8 kf = *(const bf16x8*)(
              &sK[cur][(ko + ni * 16 + row) * 64 + (((kk * 4 + g4) ^ (row & 7)) << 3)]);
          sc[0][ni] = MFMA16(kf, qf[0][kk], sc[0][ni]);
          sc[1][ni] = MFMA16(kf, qf[1][kk], sc[1][ni]);
        }
      __builtin_amdgcn_s_setprio(0);

      // ---- softmax (static max) + in-register P (pi-trick A-frags) ----
      bf16x8 pa[2][2];
      const bool diag = (kt == qi);
#pragma unroll
      for (int mi = 0; mi < 2; ++mi) {
        float ls = 0.f;
        if (!diag) {
#pragma unroll
          for (int kk2 = 0; kk2 < 2; ++kk2) {
            U8 t;
#pragma unroll
            for (int b = 0; b < 2; ++b) {
              const f32x4 s4 = sc[mi][kk2 * 2 + b];
              const float p0 = __builtin_amdgcn_exp2f(fmaf(s4[0], C1, C2));
              const float p1 = __builtin_amdgcn_exp2f(fmaf(s4[1], C1, C2));
              const float p2 = __builtin_amdgcn_exp2f(fmaf(s4[2], C1, C2));
              const float p3 = __builtin_amdgcn_exp2f(fmaf(s4[3], C1, C2));
              ls += (p0 + p1) + (p2 + p3);
              t.u[b * 2 + 0] = cvtpk(p0, p1);
              t.u[b * 2 + 1] = cvtpk(p2, p3);
            }
            pa[mi][kk2] = t.v;
          }
        } else {
          const int relB = ko + 4 * g4 - (qg * 32 + mi * 16 + row);
#pragma unroll
          for (int kk2 = 0; kk2 < 2; ++kk2) {
            U8 t;
#pragma unroll
            for (int b = 0; b < 2; ++b) {
              const f32x4 s4 = sc[mi][kk2 * 2 + b];
              const int base = relB + (kk2 * 2 + b) * 16;
              float t0 = fmaf(s4[0], C1, C2); if (base + 0 > 0) t0 = -1e30f;
              float t1 = fmaf(s4[1], C1, C2); if (base + 1 > 0) t1 = -1e30f;
              float t2 = fmaf(s4[2], C1, C2); if (base + 2 > 0) t2 = -1e30f;
              float t3 = fmaf(s4[3], C1, C2); if (base + 3 > 0) t3 = -1e30f;
              const float p0 = __builtin_amdgcn_exp2f(t0);
              const float p1 = __builtin_amdgcn_exp2f(t1);
              const float p2 = __builtin_amdgcn_exp2f(t2);
              const float p3 = __builtin_amdgcn_exp2f(t3);
              ls += (p0 + p1) + (p2 + p3);
              t.u[b * 2 + 0] = cvtpk(p0, p1);
              t.u[b * 2 + 1] = cvtpk(p2, p3);
            }
            pa[mi][kk2] = t.v;
          }
        }
        lsum[mi] += ls;
      }

      // ---- PV: O[32 q][64 d] += P * V ----
      __builtin_amdgcn_s_setprio(1);
#pragma unroll
      for (int kk2 = 0; kk2 < 2; ++kk2) {
        const int c16a = kh * 8 + kk2 * 4 + (g4 >> 1);
        const int c16b = c16a + 2;
        const int h8 = (g4 & 1) * 4;
#pragma unroll
        for (int di = 0; di < 4; ++di) {
          const int d = di * 16 + row;
          const unsigned short* vr = &sVT[cur][d * 128];
          const bf16x4 vlo = *(const bf16x4*)(vr + ((c16a ^ row) << 3) + h8);
          const bf16x4 vhi = *(const bf16x4*)(vr + ((c16b ^ row) << 3) + h8);
          const bf16x8 vf = __builtin_shufflevector(vlo, vhi, 0, 1, 2, 3, 4, 5, 6, 7);
          o[0][di] = MFMA16(pa[0][kk2], vf, o[0][di]);
          o[1][di] = MFMA16(pa[1][kk2], vf, o[1][di]);
        }
      }
      __builtin_amdgcn_s_setprio(0);
      __syncthreads();
      cur ^= 1;
    }

    // ---- combine k-halves, then write ctx ----
#pragma unroll
    for (int mi = 0; mi < 2; ++mi) {
      lsum[mi] += __shfl_xor(lsum[mi], 16);
      lsum[mi] += __shfl_xor(lsum[mi], 32);
    }
    f32x4* sO4 = (f32x4*)(&sK[0][0]);
    float* sL = (float*)(&sVT[0][0]);
    float* sL2 = sL + 128;
    if (kh) {
#pragma unroll
      for (int mi = 0; mi < 2; ++mi) {
        if (g4 == 0) sL[(qg * 2 + mi) * 16 + row] = lsum[mi];
#pragma unroll
        for (int di = 0; di < 4; ++di)
          sO4[((qg * 2 + mi) * 4 + g4) * 64 + di * 16 + row] = o[mi][di];
      }
    }
    __syncthreads();
    if (!kh) {
#pragma unroll
      for (int mi = 0; mi < 2; ++mi) {
        const float lt = lsum[mi] + sL[(qg * 2 + mi) * 16 + row];
        if (g4 == 0) sL2[(qg * 2 + mi) * 16 + row] = lt;
      }
#pragma unroll
      for (int mi = 0; mi < 2; ++mi) {
        const f32x4 lv = *(const f32x4*)(sL2 + (qg * 2 + mi) * 16 + g4 * 4);
#pragma unroll
        for (int di = 0; di < 4; ++di) {
          const f32x4 po =
              o[mi][di] + sO4[((qg * 2 + mi) * 4 + g4) * 64 + di * 16 + row];
#pragma unroll
          for (int r = 0; r < 4; ++r) {
            const int ss = qw + mi * 16 + g4 * 4 + r;
            ctx[((size_t)bb * SS + ss) * DD + h * HD + di * 16 + row] =
                f2bf(po[r] * (1.f / lv[r]));
          }
        }
      }
    }
    __syncthreads();
  }
}

// ---------- kernel 4: output projection (f32 out), bf16 gload_lds core ----------
__global__ void gemm_out(const unsigned short* __restrict__ ctx,
                         const unsigned short* __restrict__ wo, float* __restrict__ Out) {
  __shared__ unsigned short sA[128 * 64] __attribute__((aligned(16)));
  __shared__ unsigned short sB[128 * 64] __attribute__((aligned(16)));
  const int lin = blockIdx.x;
  const int swz = (lin & 7) * 32 + (lin >> 3);  // 256 = 8 * 32
  const int n0 = (swz % 8) * 128, m0 = (swz / 8) * 128;
  const int w = threadIdx.x >> 6, l = threadIdx.x & 63;
  const int wr = w >> 1, wc = w & 1, row = l & 15, g4 = l >> 4;
  const int sRow = l >> 3, sCh = (l & 7) ^ sRow;
  const unsigned short* ga = ctx + (size_t)(m0 + w * 32 + sRow) * 1024 + sCh * 8;
  const unsigned short* gb = wo + (size_t)(n0 + w * 32 + sRow) * 1024 + sCh * 8;
  unsigned short* la = sA + (w * 32) * 64;
  unsigned short* lb = sB + (w * 32) * 64;
  const int rk = row & 7;
  const f32x4 z = {0.f, 0.f, 0.f, 0.f};
  f32x4 acc[4][4];
#pragma unroll
  for (int i = 0; i < 4; ++i)
#pragma unroll
    for (int j = 0; j < 4; ++j) acc[i][j] = z;
  for (int kt = 0; kt < 1024; kt += 64) {
#pragma unroll
    for (int i = 0; i < 4; ++i) {
      gload16(ga + (size_t)(i * 8) * 1024, la + (i * 8) * 64);
      gload16(gb + (size_t)(i * 8) * 1024, lb + (i * 8) * 64);
    }
    ga += 64;
    gb += 64;
    __syncthreads();
#pragma unroll
    for (int kk = 0; kk < 2; ++kk) {
      bf16x8 af[4], bfr[4];
      const int ch = ((kk * 4 + g4) ^ rk) << 3;
#pragma unroll
      for (int mi = 0; mi < 4; ++mi)
        af[mi] = *(const bf16x8*)(sA + (wr * 64 + mi * 16 + row) * 64 + ch);
#pragma unroll
      for (int ni = 0; ni < 4; ++ni)
        bfr[ni] = *(const bf16x8*)(sB + (wc * 64 + ni * 16 + row) * 64 + ch);
#pragma unroll
      for (int mi = 0; mi < 4; ++mi)
#pragma unroll
        for (int ni = 0; ni < 4; ++ni)
          acc[mi][ni] = MFMA16(af[mi], bfr[ni], acc[mi][ni]);
    }
    __syncthreads();
  }
#pragma unroll
  for (int mi = 0; mi < 4; ++mi) {
    const int mbase = m0 + wr * 64 + mi * 16 + g4 * 4;
#pragma unroll
    for (int ni = 0; ni < 4; ++ni) {
      const int c = n0 + wc * 64 + ni * 16 + row;
      float* p = Out + (size_t)mbase * DD + c;
#pragma unroll
      for (int r = 0; r < 4; ++r) p[(size_t)r * DD] = acc[mi][ni][r];
    }
  }
}

// ---------- launch ----------
extern "C" void kernel_launch(void* const* d_in, const int* in_sizes, int n_in,
                              void* d_out, int out_size, void* d_ws, size_t ws_size,
                              hipStream_t stream) {
  (void)in_sizes; (void)n_in; (void)out_size; (void)ws_size;
  const float* q  = (const float*)d_in[0];
  const float* k  = (const float*)d_in[1];
  const float* v  = (const float*)d_in[2];
  // d_in[3] = causal mask, recomputed analytically
  const float* Wq = (const float*)d_in[4];
  const float* Wk = (const float*)d_in[5];
  const float* Wv = (const float*)d_in[6];
  const float* Wo = (const float*)d_in[7];

  unsigned short* ws = (unsigned short*)d_ws;
  const size_t NTD = (size_t)MTOK * DD;  // 4096*1024
  unsigned short* qb   = ws;
  unsigned short* kb   = qb + NTD;
  unsigned short* vb   = kb + NTD;
  unsigned short* wqkv = vb + NTD;
  unsigned short* wo   = wqkv + (size_t)3 * DD * DD;
  unsigned short* Qh   = wo + (size_t)DD * DD;
  unsigned short* Kh   = Qh + NTD;
  unsigned short* Vt   = Kh + NTD;
  unsigned short* ctx  = Vt + NTD;  // total 64MB of ws

  cvt_all<<<dim3(2048, 7), 256, 0, stream>>>(q, k, v, Wq, Wk, Wv, Wo,
                                             qb, kb, vb, wqkv, wo);
  gemm_qkv<<<192, 512, 0, stream>>>(qb, kb, vb, wqkv, Qh, Kh, Vt);
  attn_fwd<<<dim3(32, 8), 512, 0, stream>>>(Qh, Kh, Vt, ctx);
  gemm_out<<<256, 256, 0, stream>>>(ctx, wo, (float*)d_out);
}

// Round 11
// 103.014 us; speedup vs baseline: 1.5719x; 1.0800x over previous
//
#include <hip/hip_runtime.h>
#include <hip/hip_bf16.h>
#include <stdint.h>
#include <stddef.h>

// ---------- types ----------
typedef short bf16x8 __attribute__((ext_vector_type(8)));   // 8 bf16 (4 VGPRs)
typedef short bf16x4 __attribute__((ext_vector_type(4)));   // 4 bf16 (2 VGPRs)
typedef float f32x4 __attribute__((ext_vector_type(4)));
typedef unsigned short us4 __attribute__((ext_vector_type(4)));

#define MFMA16(a, b, c) __builtin_amdgcn_mfma_f32_16x16x32_bf16((a), (b), (c), 0, 0, 0)

static constexpr int BB = 2, SS = 2048, DD = 1024, HH = 16, HD = 64;
static constexpr int MTOK = BB * SS;  // 4096

union U8 { unsigned int u[4]; bf16x8 v; };

// f32 -> bf16 round-to-nearest-even
__device__ __forceinline__ unsigned short f2bf(float x) {
  unsigned int u = __float_as_uint(x);
  u += 0x7fffu + ((u >> 16) & 1u);
  return (unsigned short)(u >> 16);
}

// pack 2 f32 -> 2 bf16 in one inst (lo -> bits[15:0])
__device__ __forceinline__ unsigned int cvtpk(float lo, float hi) {
  unsigned int r;
  asm("v_cvt_pk_bf16_f32 %0, %1, %2" : "=v"(r) : "v"(lo), "v"(hi));
  return r;
}

// async global->LDS, 16B per lane; LDS dest is wave-uniform base (+lane*16 by HW)
__device__ __forceinline__ void gload16(const void* g, void* l) {
  __builtin_amdgcn_global_load_lds(
      (const __attribute__((address_space(1))) void*)g,
      (__attribute__((address_space(3))) void*)l, 16, 0, 0);
}

// ---------- kernel 1: f32 -> bf16 conversions (q,k,v,Wq,Wk,Wv,Wo) ----------
__global__ void cvt_all(const float* __restrict__ q, const float* __restrict__ k,
                        const float* __restrict__ v, const float* __restrict__ Wq,
                        const float* __restrict__ Wk, const float* __restrict__ Wv,
                        const float* __restrict__ Wo, unsigned short* __restrict__ qb,
                        unsigned short* __restrict__ kb, unsigned short* __restrict__ vb,
                        unsigned short* __restrict__ wqkv, unsigned short* __restrict__ wo) {
  const int job = blockIdx.y;
  const float* src;
  unsigned short* dst;
  int n;
  switch (job) {
    case 0: src = q;  dst = qb;             n = MTOK * DD; break;
    case 1: src = k;  dst = kb;             n = MTOK * DD; break;
    case 2: src = v;  dst = vb;             n = MTOK * DD; break;
    case 3: src = Wq; dst = wqkv;           n = DD * DD;   break;
    case 4: src = Wk; dst = wqkv + DD * DD; n = DD * DD;   break;
    case 5: src = Wv; dst = wqkv + 2 * DD * DD; n = DD * DD; break;
    default: src = Wo; dst = wo;            n = DD * DD;   break;
  }
  const int i = (blockIdx.x * 256 + threadIdx.x) * 8;
  if (i >= n) return;
  const float4 a = *(const float4*)(src + i);
  const float4 b = *(const float4*)(src + i + 4);
  bf16x8 o;
  o[0] = (short)f2bf(a.x); o[1] = (short)f2bf(a.y);
  o[2] = (short)f2bf(a.z); o[3] = (short)f2bf(a.w);
  o[4] = (short)f2bf(b.x); o[5] = (short)f2bf(b.y);
  o[6] = (short)f2bf(b.z); o[7] = (short)f2bf(b.w);
  *(bf16x8*)(dst + i) = o;
}

// ---------- shared GEMM core: C[128x128] += A[m0..][k] * B[n0..][k]^T, K=1024 ----------
// R4's measured-best core (31us, 0 conflicts): BK=64, XOR-swizzled LDS tiles
// [128][64] (slot s of row r holds global chunk s^(r&7); pre-swizzled global
// source, matched read XOR -> net identity). 16 iters, 2 barriers each.
// Implicit multi-block TLP (~3 blk/CU) hides staging latency (m114).
__device__ __forceinline__ void gemm_core(const unsigned short* __restrict__ A,
                                          const unsigned short* __restrict__ Bm,
                                          unsigned short* sA, unsigned short* sB,
                                          int m0, int n0, f32x4 (&acc)[4][4]) {
  const int w = threadIdx.x >> 6, l = threadIdx.x & 63;
  const int wr = w >> 1, wc = w & 1;
  const int row = l & 15, g4 = l >> 4;
  const int sRow = l >> 3;            // row within 8-row group
  const int sCh  = (l & 7) ^ sRow;    // global chunk fetched into LDS slot (l&7)
  const unsigned short* ga = A + (size_t)(m0 + w * 32 + sRow) * 1024 + sCh * 8;
  const unsigned short* gb = Bm + (size_t)(n0 + w * 32 + sRow) * 1024 + sCh * 8;
  unsigned short* la = sA + (w * 32) * 64;
  unsigned short* lb = sB + (w * 32) * 64;
  const int rk = (row & 7);           // read-side XOR key
  for (int kt = 0; kt < 1024; kt += 64) {
#pragma unroll
    for (int i = 0; i < 4; ++i) {
      gload16(ga + (size_t)(i * 8) * 1024, la + (i * 8) * 64);
      gload16(gb + (size_t)(i * 8) * 1024, lb + (i * 8) * 64);
    }
    ga += 64;
    gb += 64;
    __syncthreads();  // vmcnt drain -> tile ready
#pragma unroll
    for (int kk = 0; kk < 2; ++kk) {
      bf16x8 af[4], bfr[4];
      const int ch = ((kk * 4 + g4) ^ rk) << 3;
#pragma unroll
      for (int mi = 0; mi < 4; ++mi)
        af[mi] = *(const bf16x8*)(sA + (wr * 64 + mi * 16 + row) * 64 + ch);
#pragma unroll
      for (int ni = 0; ni < 4; ++ni)
        bfr[ni] = *(const bf16x8*)(sB + (wc * 64 + ni * 16 + row) * 64 + ch);
#pragma unroll
      for (int mi = 0; mi < 4; ++mi)
#pragma unroll
        for (int ni = 0; ni < 4; ++ni)
          acc[mi][ni] = MFMA16(af[mi], bfr[ni], acc[mi][ni]);
    }
    __syncthreads();  // reads done before next stage
  }
}

// ---------- kernel 2: fused QKV projection (R4 data path, measured 31us) ----------
__global__ void gemm_qkv(const unsigned short* __restrict__ qb,
                         const unsigned short* __restrict__ kb,
                         const unsigned short* __restrict__ vb,
                         const unsigned short* __restrict__ wqkv,
                         unsigned short* __restrict__ Qh, unsigned short* __restrict__ Kh,
                         unsigned short* __restrict__ Vt) {
  __shared__ unsigned short sA[128 * 64] __attribute__((aligned(16)));
  __shared__ unsigned short sB[128 * 64] __attribute__((aligned(16)));
  const int lin = blockIdx.x;
  const int swz = (lin & 7) * 96 + (lin >> 3);  // 768 = 8 * 96 (bijective XCD swizzle)
  const int n0 = (swz % 24) * 128, m0 = (swz / 24) * 128;
  const int proj = n0 >> 10;  // 0:Q 1:K 2:V
  const unsigned short* A = proj == 0 ? qb : (proj == 1 ? kb : vb);
  const f32x4 z = {0.f, 0.f, 0.f, 0.f};
  f32x4 acc[4][4];
#pragma unroll
  for (int i = 0; i < 4; ++i)
#pragma unroll
    for (int j = 0; j < 4; ++j) acc[i][j] = z;
  gemm_core(A, wqkv, sA, sB, m0, n0, acc);
  const int w = threadIdx.x >> 6, l = threadIdx.x & 63;
  const int wr = w >> 1, wc = w & 1, row = l & 15, g4 = l >> 4;
#pragma unroll
  for (int mi = 0; mi < 4; ++mi) {
    const int mbase = m0 + wr * 64 + mi * 16 + g4 * 4;  // token row
    const int bb = mbase >> 11, ss = mbase & 2047;
#pragma unroll
    for (int ni = 0; ni < 4; ++ni) {
      const int c = n0 + wc * 64 + ni * 16 + row;
      const int cc = c & 1023, h = cc >> 6, d = cc & 63;
      if (proj == 0) {
        unsigned short* p = Qh + (((size_t)bb * HH + h) * SS + ss) * HD + d;
#pragma unroll
        for (int r = 0; r < 4; ++r) p[(size_t)r * HD] = f2bf(acc[mi][ni][r]);
      } else if (proj == 1) {
        unsigned short* p = Kh + (((size_t)bb * HH + h) * SS + ss) * HD + d;
#pragma unroll
        for (int r = 0; r < 4; ++r) p[(size_t)r * HD] = f2bf(acc[mi][ni][r]);
      } else {
        us4 pk;
#pragma unroll
        for (int r = 0; r < 4; ++r) pk[r] = f2bf(acc[mi][ni][r]);
        *(us4*)(Vt + (((size_t)bb * HH + h) * HD + d) * SS + ss) = pk;
      }
    }
  }
}

// ---------- kernel 3: causal flash attention (R5 paired version — measured best) ----------
__global__ __launch_bounds__(512, 2) void attn_fwd(const unsigned short* __restrict__ Qh,
                                                   const unsigned short* __restrict__ Kh,
                                                   const unsigned short* __restrict__ Vt,
                                                   unsigned short* __restrict__ ctx) {
  __shared__ unsigned short sK[2][128 * 64] __attribute__((aligned(16)));   // 2x16KB
  __shared__ unsigned short sVT[2][64 * 128] __attribute__((aligned(16)));  // 2x16KB
  const int w = threadIdx.x >> 6, l = threadIdx.x & 63;
  const int row = l & 15, g4 = l >> 4;
  const int qg = w & 3, kh = w >> 2;   // q-group, k-half
  const int ko = kh * 64;              // k offset within tile
  const int bh = blockIdx.x, pair = blockIdx.y;
  const size_t bhS = (size_t)bh * SS;
  const int bb = bh >> 4, h = bh & 15;

  const int kLane = l >> 3;            // staging: row-in-group 0..7 (K tile)
  const int kCh = (l & 7) ^ kLane;     // fetched chunk16 (key = row&7)
  const unsigned short* gvBase = Vt + (size_t)bh * HD * SS;

  const f32x4 z = {0.f, 0.f, 0.f, 0.f};
  constexpr float C1 = 0.18033688f;    // 0.125 * log2(e)
  constexpr float C2 = -17.3123405f;   // -12 * log2(e)

  for (int half = 0; half < 2; ++half) {
    const int qi = half ? (15 - pair) : pair;
    const int q0 = qi * 128;
    const int qw = q0 + qg * 32;       // wave's q base (32 rows)

    bf16x8 qf[2][2];
#pragma unroll
    for (int mi = 0; mi < 2; ++mi)
#pragma unroll
      for (int kk = 0; kk < 2; ++kk)
        qf[mi][kk] = *(const bf16x8*)(Qh + (bhS + qw + mi * 16 + row) * HD +
                                      kk * 32 + g4 * 8);

    f32x4 o[2][4];
#pragma unroll
    for (int mi = 0; mi < 2; ++mi)
#pragma unroll
      for (int di = 0; di < 4; ++di) o[mi][di] = z;
    float lsum[2] = {0.f, 0.f};

    // ---- stage tile 0 into buf 0 ----
    {
      const unsigned short* gk = Kh + (bhS + 0) * HD;
      const unsigned short* gv = gvBase;
#pragma unroll
      for (int i = 0; i < 2; ++i) {
        const int R = w * 16 + i * 8;
        gload16(gk + (size_t)(R + kLane) * HD + kCh * 8, &sK[0][R * 64]);
      }
#pragma unroll
      for (int i = 0; i < 2; ++i) {
        const int R = w * 8 + i * 4;
        const int vrow = R + g4;
        gload16(gv + (size_t)vrow * SS + ((row ^ (vrow & 15)) * 8), &sVT[0][R * 128]);
      }
    }
    __syncthreads();
    int cur = 0;

    for (int kt = 0; kt <= qi; ++kt) {
      // ---- prefetch next tile into other buffer (in flight across compute) ----
      if (kt < qi) {
        const unsigned short* gk = Kh + (bhS + (kt + 1) * 128) * HD;
        const unsigned short* gv = gvBase + (kt + 1) * 128;
        const int nb = cur ^ 1;
#pragma unroll
        for (int i = 0; i < 2; ++i) {
          const int R = w * 16 + i * 8;
          gload16(gk + (size_t)(R + kLane) * HD + kCh * 8, &sK[nb][R * 64]);
        }
#pragma unroll
        for (int i = 0; i < 2; ++i) {
          const int R = w * 8 + i * 4;
          const int vrow = R + g4;
          gload16(gv + (size_t)vrow * SS + ((row ^ (vrow & 15)) * 8), &sVT[nb][R * 128]);
        }
      }

      // ---- QK^T (swapped): sc[mi][ni]: k = ko+ni*16+4*g4+r, q = qw+mi*16+row ----
      f32x4 sc[2][4];
#pragma unroll
      for (int mi = 0; mi < 2; ++mi)
#pragma unroll
        for (int ni = 0; ni < 4; ++ni) sc[mi][ni] = z;
      __builtin_amdgcn_s_setprio(1);
#pragma unroll
      for (int kk = 0; kk < 2; ++kk)
#pragma unroll
        for (int ni = 0; ni < 4; ++ni) {
          const bf16x8 kf = *(const bf16x8*)(
              &sK[cur][(ko + ni * 16 + row) * 64 + (((kk * 4 + g4) ^ (row & 7)) << 3)]);
          sc[0][ni] = MFMA16(kf, qf[0][kk], sc[0][ni]);
          sc[1][ni] = MFMA16(kf, qf[1][kk], sc[1][ni]);
        }
      __builtin_amdgcn_s_setprio(0);

      // ---- softmax (static max) + in-register P (pi-trick A-frags) ----
      bf16x8 pa[2][2];
      const bool diag = (kt == qi);
#pragma unroll
      for (int mi = 0; mi < 2; ++mi) {
        float ls = 0.f;
        if (!diag) {
#pragma unroll
          for (int kk2 = 0; kk2 < 2; ++kk2) {
            U8 t;
#pragma unroll
            for (int b = 0; b < 2; ++b) {
              const f32x4 s4 = sc[mi][kk2 * 2 + b];
              const float p0 = __builtin_amdgcn_exp2f(fmaf(s4[0], C1, C2));
              const float p1 = __builtin_amdgcn_exp2f(fmaf(s4[1], C1, C2));
              const float p2 = __builtin_amdgcn_exp2f(fmaf(s4[2], C1, C2));
              const float p3 = __builtin_amdgcn_exp2f(fmaf(s4[3], C1, C2));
              ls += (p0 + p1) + (p2 + p3);
              t.u[b * 2 + 0] = cvtpk(p0, p1);
              t.u[b * 2 + 1] = cvtpk(p2, p3);
            }
            pa[mi][kk2] = t.v;
          }
        } else {  // diag tile: mask k > q
          const int relB = ko + 4 * g4 - (qg * 32 + mi * 16 + row);
#pragma unroll
          for (int kk2 = 0; kk2 < 2; ++kk2) {
            U8 t;
#pragma unroll
            for (int b = 0; b < 2; ++b) {
              const f32x4 s4 = sc[mi][kk2 * 2 + b];
              const int base = relB + (kk2 * 2 + b) * 16;
              float t0 = fmaf(s4[0], C1, C2); if (base + 0 > 0) t0 = -1e30f;
              float t1 = fmaf(s4[1], C1, C2); if (base + 1 > 0) t1 = -1e30f;
              float t2 = fmaf(s4[2], C1, C2); if (base + 2 > 0) t2 = -1e30f;
              float t3 = fmaf(s4[3], C1, C2); if (base + 3 > 0) t3 = -1e30f;
              const float p0 = __builtin_amdgcn_exp2f(t0);
              const float p1 = __builtin_amdgcn_exp2f(t1);
              const float p2 = __builtin_amdgcn_exp2f(t2);
              const float p3 = __builtin_amdgcn_exp2f(t3);
              ls += (p0 + p1) + (p2 + p3);
              t.u[b * 2 + 0] = cvtpk(p0, p1);
              t.u[b * 2 + 1] = cvtpk(p2, p3);
            }
            pa[mi][kk2] = t.v;
          }
        }
        lsum[mi] += ls;
      }

      // ---- PV: O[32 q][64 d] += P * V ; vf built per-lane to match pa's k-perm ----
      __builtin_amdgcn_s_setprio(1);
#pragma unroll
      for (int kk2 = 0; kk2 < 2; ++kk2) {
        const int c16a = kh * 8 + kk2 * 4 + (g4 >> 1);  // b=0 chunk16 (global)
        const int c16b = c16a + 2;                      // b=1 chunk16
        const int h8 = (g4 & 1) * 4;                    // 8B half within chunk
#pragma unroll
        for (int di = 0; di < 4; ++di) {
          const int d = di * 16 + row;
          const unsigned short* vr = &sVT[cur][d * 128];
          const bf16x4 vlo = *(const bf16x4*)(vr + ((c16a ^ row) << 3) + h8);
          const bf16x4 vhi = *(const bf16x4*)(vr + ((c16b ^ row) << 3) + h8);
          const bf16x8 vf = __builtin_shufflevector(vlo, vhi, 0, 1, 2, 3, 4, 5, 6, 7);
          o[0][di] = MFMA16(pa[0][kk2], vf, o[0][di]);
          o[1][di] = MFMA16(pa[1][kk2], vf, o[1][di]);
        }
      }
      __builtin_amdgcn_s_setprio(0);
      __syncthreads();  // buffer-reuse fence + drains prefetch
      cur ^= 1;
    }

    // ---- combine k-halves (static max -> pure addition), then write ctx ----
#pragma unroll
    for (int mi = 0; mi < 2; ++mi) {
      lsum[mi] += __shfl_xor(lsum[mi], 16);
      lsum[mi] += __shfl_xor(lsum[mi], 32);  // full sum over this k-half
    }
    f32x4* sO4 = (f32x4*)(&sK[0][0]);        // 2048 slots = 32KB scratch
    float* sL = (float*)(&sVT[0][0]);        // 128 f32: hi-half lsums
    float* sL2 = sL + 128;                   // 128 f32: totals
    if (kh) {
#pragma unroll
      for (int mi = 0; mi < 2; ++mi) {
        if (g4 == 0) sL[(qg * 2 + mi) * 16 + row] = lsum[mi];
#pragma unroll
        for (int di = 0; di < 4; ++di)
          sO4[((qg * 2 + mi) * 4 + g4) * 64 + di * 16 + row] = o[mi][di];
      }
    }
    __syncthreads();
    if (!kh) {
#pragma unroll
      for (int mi = 0; mi < 2; ++mi) {
        const float lt = lsum[mi] + sL[(qg * 2 + mi) * 16 + row];
        if (g4 == 0) sL2[(qg * 2 + mi) * 16 + row] = lt;  // redistribute to PV q-map
      }
#pragma unroll
      for (int mi = 0; mi < 2; ++mi) {
        const f32x4 lv = *(const f32x4*)(sL2 + (qg * 2 + mi) * 16 + g4 * 4);
#pragma unroll
        for (int di = 0; di < 4; ++di) {
          const f32x4 po =
              o[mi][di] + sO4[((qg * 2 + mi) * 4 + g4) * 64 + di * 16 + row];
#pragma unroll
          for (int r = 0; r < 4; ++r) {
            const int ss = qw + mi * 16 + g4 * 4 + r;
            ctx[((size_t)bb * SS + ss) * DD + h * HD + di * 16 + row] =
                f2bf(po[r] * (1.f / lv[r]));
          }
        }
      }
    }
    __syncthreads();  // scratch reads done before next half's staging
  }
}

// ---------- kernel 4: output projection (f32 out), XCD-swizzled ----------
__global__ void gemm_out(const unsigned short* __restrict__ ctx,
                         const unsigned short* __restrict__ wo, float* __restrict__ Out) {
  __shared__ unsigned short sA[128 * 64] __attribute__((aligned(16)));
  __shared__ unsigned short sB[128 * 64] __attribute__((aligned(16)));
  const int lin = blockIdx.x;
  const int swz = (lin & 7) * 32 + (lin >> 3);  // 256 = 8 * 32
  const int n0 = (swz % 8) * 128, m0 = (swz / 8) * 128;
  const f32x4 z = {0.f, 0.f, 0.f, 0.f};
  f32x4 acc[4][4];
#pragma unroll
  for (int i = 0; i < 4; ++i)
#pragma unroll
    for (int j = 0; j < 4; ++j) acc[i][j] = z;
  gemm_core(ctx, wo, sA, sB, m0, n0, acc);
  const int w = threadIdx.x >> 6, l = threadIdx.x & 63;
  const int wr = w >> 1, wc = w & 1, row = l & 15, g4 = l >> 4;
#pragma unroll
  for (int mi = 0; mi < 4; ++mi) {
    const int mbase = m0 + wr * 64 + mi * 16 + g4 * 4;
#pragma unroll
    for (int ni = 0; ni < 4; ++ni) {
      const int c = n0 + wc * 64 + ni * 16 + row;
      float* p = Out + (size_t)mbase * DD + c;
#pragma unroll
      for (int r = 0; r < 4; ++r) p[(size_t)r * DD] = acc[mi][ni][r];
    }
  }
}

// ---------- launch ----------
extern "C" void kernel_launch(void* const* d_in, const int* in_sizes, int n_in,
                              void* d_out, int out_size, void* d_ws, size_t ws_size,
                              hipStream_t stream) {
  (void)in_sizes; (void)n_in; (void)out_size; (void)ws_size;
  const float* q  = (const float*)d_in[0];
  const float* k  = (const float*)d_in[1];
  const float* v  = (const float*)d_in[2];
  // d_in[3] = causal mask, recomputed analytically
  const float* Wq = (const float*)d_in[4];
  const float* Wk = (const float*)d_in[5];
  const float* Wv = (const float*)d_in[6];
  const float* Wo = (const float*)d_in[7];

  unsigned short* ws = (unsigned short*)d_ws;
  const size_t NTD = (size_t)MTOK * DD;  // 4096*1024
  unsigned short* qb   = ws;
  unsigned short* kb   = qb + NTD;
  unsigned short* vb   = kb + NTD;
  unsigned short* wqkv = vb + NTD;
  unsigned short* wo   = wqkv + (size_t)3 * DD * DD;
  unsigned short* Qh   = wo + (size_t)DD * DD;
  unsigned short* Kh   = Qh + NTD;
  unsigned short* Vt   = Kh + NTD;
  unsigned short* ctx  = Vt + NTD;  // total 64MB of ws

  cvt_all<<<dim3(2048, 7), 256, 0, stream>>>(q, k, v, Wq, Wk, Wv, Wo,
                                             qb, kb, vb, wqkv, wo);
  gemm_qkv<<<768, 256, 0, stream>>>(qb, kb, vb, wqkv, Qh, Kh, Vt);
  attn_fwd<<<dim3(32, 8), 512, 0, stream>>>(Qh, Kh, Vt, ctx);
  gemm_out<<<256, 256, 0, stream>>>(ctx, wo, (float*)d_out);
}